// Round 26
// baseline (147.615 us; speedup 1.0000x reference)
//
#include <hip/hip_runtime.h>

#define BDIM 256
#define KC_STRIDE 28                  // per (case,co): K[0..24], bias at [25], 2 pad
#define CASE_STRIDE (32 * KC_STRIDE)  // 896 floats per border-case
#define SP 4100                       // S plane stride (64 rows x 64 + 4 pad)

typedef float floatx4 __attribute__((ext_vector_type(4)));

// case index along one axis: 0 (p==0), 1 (p==1), 2 (interior), 3 (p==62), 4 (p==63)
__device__ __forceinline__ int casef(int p) {
  return ((unsigned)(p - 2) < 60u) ? 2 : (p < 2 ? p : p - 59);
}

// ---------------- prep: collapsed 5x5 kernels, layout [case][co][28] ----------------
__global__ __launch_bounds__(BDIM) void prep_kernel(
    const float* __restrict__ W1, const float* __restrict__ b1,
    const float* __restrict__ W2, const float* __restrict__ b2,
    float* __restrict__ ws) {
  __shared__ float Mlds[9 * 9 * 32];
  __shared__ float BvL[9 * 32];
  const int tid = threadIdx.x;
  const int co = tid & 31;
  for (int tap = tid >> 5; tap < 9; tap += 8) {
    float acc[9] = {0.f, 0.f, 0.f, 0.f, 0.f, 0.f, 0.f, 0.f, 0.f};
    float accB = 0.f;
    for (int ci = 0; ci < 64; ++ci) {
      float w2 = W2[(tap * 64 + ci) * 32 + co];
      accB = fmaf(b1[ci], w2, accB);
#pragma unroll
      for (int e = 0; e < 9; ++e) acc[e] = fmaf(W1[e * 64 + ci], w2, acc[e]);
    }
#pragma unroll
    for (int e = 0; e < 9; ++e) Mlds[(tap * 9 + e) * 32 + co] = acc[e];
    BvL[tap * 32 + co] = accB;
  }
  __syncthreads();

  const int a = blockIdx.x / 5, c = blockIdx.x % 5;
  const int dmask[5] = {4, 6, 7, 3, 1};
  const int Da = dmask[a], Dc = dmask[c];
  for (int t = tid; t < CASE_STRIDE; t += BDIM) {
    int cc = t / KC_STRIDE, r = t % KC_STRIDE;
    float s = 0.f;
    if (r < 25) {
      int u = r / 5, v = r % 5;
      for (int di = 0; di < 3; ++di) {
        if (!((Da >> di) & 1)) continue;
        int ei = u - di;
        if ((unsigned)ei > 2u) continue;
        for (int dj = 0; dj < 3; ++dj) {
          if (!((Dc >> dj) & 1)) continue;
          int ej = v - dj;
          if ((unsigned)ej > 2u) continue;
          s += Mlds[((di * 3 + dj) * 9 + ei * 3 + ej) * 32 + cc];
        }
      }
    } else if (r == 25) {
      s = b2[cc];
      for (int di = 0; di < 3; ++di)
        if ((Da >> di) & 1)
          for (int dj = 0; dj < 3; ++dj)
            if ((Dc >> dj) & 1) s += BvL[(di * 3 + dj) * 32 + cc];
    }
    ws[blockIdx.x * CASE_STRIDE + t] = s;
  }
}

// ---- main: ONE block per full image; 4 octet substages over 64 rows;
// ---- co-paired interior, KiL-hoisted K, NT dump, lgkm-only barriers ----
__global__ __launch_bounds__(BDIM) void main_kernel(
    const float* __restrict__ x, const float* __restrict__ ws,
    float* __restrict__ out) {
  const int b = blockIdx.x;
  const int tid = threadIdx.x;
  const int lane = tid & 63;
  const int wave = tid >> 6;

  __shared__ __align__(16) float xp[68 * 68];       // rows -2..65, cols -2..65
  __shared__ __align__(16) float S[8][SP];          // 8 planes of 64x64 (+pad)
  __shared__ __align__(16) float KiL[CASE_STRIDE];  // interior case (2,2), 32 ch
  __shared__ unsigned long long Rm[64];
  __shared__ unsigned short aqi[840], aqb[184];
  __shared__ int nqi_sh, nqb_sh;

  if (tid == 0) { nqi_sh = 0; nqb_sh = 0; }
  float4* xp4 = reinterpret_cast<float4*>(xp);
  for (int i = tid; i < 68 * 68 / 4; i += BDIM) xp4[i] = make_float4(0.f, 0.f, 0.f, 0.f);
  for (int i = tid; i < CASE_STRIDE; i += BDIM) KiL[i] = ws[12 * CASE_STRIDE + i];
  __syncthreads();

  const float* xb = x + (size_t)b * 4096;
  for (int it = tid; it < 1024; it += BDIM) {
    int r = it >> 4, c4 = (it & 15) << 2;
    float4 v = *reinterpret_cast<const float4*>(xb + r * 64 + c4);
    float2* d2 = reinterpret_cast<float2*>(&xp[(2 + r) * 68 + 2 + c4]);
    d2[0] = make_float2(v.x, v.y);
    d2[1] = make_float2(v.z, v.w);
  }
  __syncthreads();

  for (int r = wave; r < 64; r += 4) {
    int pred = (xp[(2 + r) * 68 + 2 + lane] != 0.0f);
    unsigned long long m = __ballot(pred);
    if (lane == 0) Rm[r] = m;
  }
  __syncthreads();

  for (int g = tid; g < 1024; g += BDIM) {
    int p = g >> 4, q0 = (g & 15) << 2;
    unsigned bits = (unsigned)(Rm[p] >> q0) & 0xFu;
    if (!bits) continue;
    bool inter = ((unsigned)(p - 2) < 60u) && ((unsigned)(q0 - 4) <= 52u);
    if (inter) {
      aqi[atomicAdd(&nqi_sh, 1)] = (unsigned short)g;
    } else {
      aqb[atomicAdd(&nqb_sh, 1)] = (unsigned short)g;
    }
  }
  __syncthreads();

  const int nqi = nqi_sh, nqb = nqb_sh;
  float* outb = out + (size_t)b * (32 * 4096);
  const int co4 = tid & 3;

  // 4 substages: one per channel octet cg, full image each
  for (int cg = 0; cg < 4; ++cg) {
    // ---- hoist interior kernels for this lane's channel pair from LDS ----
    const int co_lo = (cg << 3) + co4;
    float KA[26], KB[26];
    {
      const float* KpA = &KiL[co_lo * KC_STRIDE];
      const float* KpB = &KiL[(co_lo + 4) * KC_STRIDE];
#pragma unroll
      for (int j = 0; j < 26; ++j) { KA[j] = KpA[j]; KB[j] = KpB[j]; }
    }
    // ---- interior quads: item = (quad, co4); thread computes co and co+4 ----
    for (int n = tid; n < nqi * 4; n += BDIM) {
      int g = aqi[n >> 2];
      int k = g >> 4, q0 = (g & 15) << 2;
      float ba = KA[25], bbv = KB[25];
      float a0 = ba, a1 = ba, a2 = ba, a3 = ba;
      float b0 = bbv, b1 = bbv, b2 = bbv, b3 = bbv;
#pragma unroll
      for (int u = 0; u < 5; ++u) {
        const float* xr = &xp[(k + u) * 68 + q0];
        float4 xa = *reinterpret_cast<const float4*>(xr);
        float4 xc = *reinterpret_cast<const float4*>(xr + 4);
        float xv[8] = {xa.x, xa.y, xa.z, xa.w, xc.x, xc.y, xc.z, xc.w};
#pragma unroll
        for (int v = 0; v < 5; ++v) {
          float ka = KA[u * 5 + v], kb = KB[u * 5 + v];
          a0 = fmaf(xv[v], ka, a0);
          a1 = fmaf(xv[v + 1], ka, a1);
          a2 = fmaf(xv[v + 2], ka, a2);
          a3 = fmaf(xv[v + 3], ka, a3);
          b0 = fmaf(xv[v], kb, b0);
          b1 = fmaf(xv[v + 1], kb, b1);
          b2 = fmaf(xv[v + 2], kb, b2);
          b3 = fmaf(xv[v + 3], kb, b3);
        }
      }
      int so = (k << 6) + q0;
      *reinterpret_cast<float4*>(&S[co4][so]) = make_float4(a0, a1, a2, a3);
      *reinterpret_cast<float4*>(&S[co4 + 4][so]) = make_float4(b0, b1, b2, b3);
    }
    // ---- border quads: item = (quad, cs of 8); per-pixel case, K from L2 ----
    for (int n = tid; n < nqb * 8; n += BDIM) {
      int g = aqb[n >> 3];
      int cs = n & 7;  // lane-static
      int co = (cg << 3) + cs;
      int k = g >> 4, q0 = (g & 15) << 2;
      int cp = casef(k);
      const float* K0 = ws + ((cp * 5 + casef(q0)) * 32 + co) * KC_STRIDE;
      const float* K1 = ws + ((cp * 5 + casef(q0 + 1)) * 32 + co) * KC_STRIDE;
      const float* K2 = ws + ((cp * 5 + casef(q0 + 2)) * 32 + co) * KC_STRIDE;
      const float* K3 = ws + ((cp * 5 + casef(q0 + 3)) * 32 + co) * KC_STRIDE;
      float z0 = K0[25], z1 = K1[25], z2 = K2[25], z3 = K3[25];
#pragma unroll
      for (int u = 0; u < 5; ++u) {
        const float* xr = &xp[(k + u) * 68 + q0];
        float4 xa = *reinterpret_cast<const float4*>(xr);
        float4 xc = *reinterpret_cast<const float4*>(xr + 4);
        float xv[8] = {xa.x, xa.y, xa.z, xa.w, xc.x, xc.y, xc.z, xc.w};
#pragma unroll
        for (int v = 0; v < 5; ++v) {
          int o = u * 5 + v;
          z0 = fmaf(xv[v], K0[o], z0);
          z1 = fmaf(xv[v + 1], K1[o], z1);
          z2 = fmaf(xv[v + 2], K2[o], z2);
          z3 = fmaf(xv[v + 3], K3[o], z3);
        }
      }
      *reinterpret_cast<float4*>(&S[cs][(k << 6) + q0]) =
          make_float4(z0, z1, z2, z3);
    }
    // ---- drain-free barrier: LDS visibility only; stores stay in flight ----
    asm volatile("s_waitcnt lgkmcnt(0)" ::: "memory");
    __builtin_amdgcn_s_barrier();
    // ---- dump: wave w -> planes w and w+4 (full 64x64 each), NT stores ----
    {
      int co_a = (cg << 3) + wave;
      float* dstA = outb + (((size_t)co_a) << 12);
      float* dstB = outb + (((size_t)(co_a + 4)) << 12);
      const floatx4* SpA = reinterpret_cast<const floatx4*>(&S[wave][0]);
      const floatx4* SpB = reinterpret_cast<const floatx4*>(&S[wave + 4][0]);
#pragma unroll
      for (int i = 0; i < 16; ++i) {
        int f4 = (i << 6) + lane;
        int kk = f4 >> 4, q0 = (f4 & 15) << 2;
        unsigned bits = (unsigned)(Rm[kk] >> q0) & 0xFu;
        floatx4 va = SpA[f4];
        floatx4 vb = SpB[f4];
        if (!(bits & 1u)) { va.x = 0.f; vb.x = 0.f; }
        if (!(bits & 2u)) { va.y = 0.f; vb.y = 0.f; }
        if (!(bits & 4u)) { va.z = 0.f; vb.z = 0.f; }
        if (!(bits & 8u)) { va.w = 0.f; vb.w = 0.f; }
        __builtin_nontemporal_store(va, reinterpret_cast<floatx4*>(dstA + (f4 << 2)));
        __builtin_nontemporal_store(vb, reinterpret_cast<floatx4*>(dstB + (f4 << 2)));
      }
    }
    // ---- WAR barrier before next substage overwrites S ----
    asm volatile("s_waitcnt lgkmcnt(0)" ::: "memory");
    __builtin_amdgcn_s_barrier();
  }
}

extern "C" void kernel_launch(void* const* d_in, const int* in_sizes, int n_in,
                              void* d_out, int out_size, void* d_ws, size_t ws_size,
                              hipStream_t stream) {
  const float* x  = (const float*)d_in[0];
  const float* W1 = (const float*)d_in[1];
  const float* b1 = (const float*)d_in[2];
  const float* W2 = (const float*)d_in[3];
  const float* b2 = (const float*)d_in[4];
  float* out = (float*)d_out;
  float* ws  = (float*)d_ws;
  int B = in_sizes[0] / 4096;  // 1024 images of 64x64x1

  hipLaunchKernelGGL(prep_kernel, dim3(25), dim3(BDIM), 0, stream, W1, b1, W2, b2, ws);
  hipLaunchKernelGGL(main_kernel, dim3(B), dim3(BDIM), 0, stream, x, ws, out);
}

// Round 27
// 121.619 us; speedup vs baseline: 1.2138x; 1.2138x over previous
//
#include <hip/hip_runtime.h>

#define BDIM 256
#define KC_STRIDE 28                  // per (case,co): K[0..24], bias at [25], 2 pad
#define CASE_STRIDE (32 * KC_STRIDE)  // 896 floats per border-case
#define SP 2052                       // S plane stride (32 rows x 64 + 4 pad)

typedef float floatx4 __attribute__((ext_vector_type(4)));

// case index along one axis: 0 (p==0), 1 (p==1), 2 (interior), 3 (p==62), 4 (p==63)
__device__ __forceinline__ int casef(int p) {
  return ((unsigned)(p - 2) < 60u) ? 2 : (p < 2 ? p : p - 59);
}

// spread 16 bits to stride-4 positions (bit i -> bit 4i)
__device__ __forceinline__ unsigned long long spread4(unsigned x) {
  unsigned long long v = x & 0xFFFFull;
  v = (v | (v << 24)) & 0x000000FF000000FFull;
  v = (v | (v << 12)) & 0x000F000F000F000Full;
  v = (v | (v << 6))  & 0x0303030303030303ull;
  v = (v | (v << 3))  & 0x1111111111111111ull;
  return v;
}

// ---------------- prep: collapsed 5x5 kernels, layout [case][co][28] ----------------
__global__ __launch_bounds__(BDIM) void prep_kernel(
    const float* __restrict__ W1, const float* __restrict__ b1,
    const float* __restrict__ W2, const float* __restrict__ b2,
    float* __restrict__ ws) {
  __shared__ float Mlds[9 * 9 * 32];
  __shared__ float BvL[9 * 32];
  const int tid = threadIdx.x;
  const int co = tid & 31;
  for (int tap = tid >> 5; tap < 9; tap += 8) {
    float acc[9] = {0.f, 0.f, 0.f, 0.f, 0.f, 0.f, 0.f, 0.f, 0.f};
    float accB = 0.f;
    for (int ci = 0; ci < 64; ++ci) {
      float w2 = W2[(tap * 64 + ci) * 32 + co];
      accB = fmaf(b1[ci], w2, accB);
#pragma unroll
      for (int e = 0; e < 9; ++e) acc[e] = fmaf(W1[e * 64 + ci], w2, acc[e]);
    }
#pragma unroll
    for (int e = 0; e < 9; ++e) Mlds[(tap * 9 + e) * 32 + co] = acc[e];
    BvL[tap * 32 + co] = accB;
  }
  __syncthreads();

  const int a = blockIdx.x / 5, c = blockIdx.x % 5;
  const int dmask[5] = {4, 6, 7, 3, 1};
  const int Da = dmask[a], Dc = dmask[c];
  for (int t = tid; t < CASE_STRIDE; t += BDIM) {
    int cc = t / KC_STRIDE, r = t % KC_STRIDE;
    float s = 0.f;
    if (r < 25) {
      int u = r / 5, v = r % 5;
      for (int di = 0; di < 3; ++di) {
        if (!((Da >> di) & 1)) continue;
        int ei = u - di;
        if ((unsigned)ei > 2u) continue;
        for (int dj = 0; dj < 3; ++dj) {
          if (!((Dc >> dj) & 1)) continue;
          int ej = v - dj;
          if ((unsigned)ej > 2u) continue;
          s += Mlds[((di * 3 + dj) * 9 + ei * 3 + ej) * 32 + cc];
        }
      }
    } else if (r == 25) {
      s = b2[cc];
      for (int di = 0; di < 3; ++di)
        if ((Da >> di) & 1)
          for (int dj = 0; dj < 3; ++dj)
            if ((Dc >> dj) & 1) s += BvL[(di * 3 + dj) * 32 + cc];
    }
    ws[blockIdx.x * CASE_STRIDE + t] = s;
  }
}

// ---- main: R24 substage loop + compressed prologue (fused load+ballot,
// ---- halo-only zero-fill, 2 barriers instead of 4) ----
__global__ __launch_bounds__(BDIM) void main_kernel(
    const float* __restrict__ x, const float* __restrict__ ws,
    float* __restrict__ out) {
  const int bb = blockIdx.x;
  const int b = bb >> 1;
  const int r0 = (bb & 1) << 5;  // 0 or 32
  const int tid = threadIdx.x;
  const int lane = tid & 63;
  const int wave = tid >> 6;

  __shared__ __align__(16) float xp[36 * 68];       // rows r0-2..r0+33, cols -2..65
  __shared__ __align__(16) float S[8][SP];          // 8 planes of 32x64 (+pad)
  __shared__ __align__(16) float KiL[CASE_STRIDE];  // interior case (2,2), 32 ch
  __shared__ unsigned long long Rm[32];
  __shared__ unsigned short aqi[448], aqb[128];
  __shared__ int nqi_sh, nqb_sh;

  if (tid == 0) { nqi_sh = 0; nqb_sh = 0; }
  for (int i = tid; i < CASE_STRIDE; i += BDIM) KiL[i] = ws[12 * CASE_STRIDE + i];

  const float* xb = x + (size_t)b * 4096;

  // ---- col-halo zero (cols 0,1,66,67 of all 36 xp rows; 144 floats) ----
  if (tid < 144) {
    int i = tid >> 2, c = tid & 3;
    xp[i * 68 + ((c & 1) + ((c >> 1) * 66))] = 0.f;
  }
  // ---- fused own-row load + ballot (rows r0..r0+31, always in-bounds) ----
#pragma unroll
  for (int j = 0; j < 2; ++j) {
    int it = tid + (j << 8);
    int k = it >> 4;           // 0..31 own-row index
    int q = it & 15;           // quad
    float4 v = *reinterpret_cast<const float4*>(xb + (r0 + k) * 64 + (q << 2));
    float2* d2 = reinterpret_cast<float2*>(&xp[(k + 2) * 68 + 2 + (q << 2)]);
    d2[0] = make_float2(v.x, v.y);
    d2[1] = make_float2(v.z, v.w);
    unsigned long long b0 = __ballot(v.x != 0.f);
    unsigned long long b1 = __ballot(v.y != 0.f);
    unsigned long long b2 = __ballot(v.z != 0.f);
    unsigned long long b3 = __ballot(v.w != 0.f);
    if ((lane & 15) == 0) {
      int rslice = lane >> 4;
      unsigned s0 = (unsigned)((b0 >> (rslice << 4)) & 0xFFFFu);
      unsigned s1 = (unsigned)((b1 >> (rslice << 4)) & 0xFFFFu);
      unsigned s2 = (unsigned)((b2 >> (rslice << 4)) & 0xFFFFu);
      unsigned s3 = (unsigned)((b3 >> (rslice << 4)) & 0xFFFFu);
      Rm[k] = spread4(s0) | (spread4(s1) << 1) | (spread4(s2) << 2) |
              (spread4(s3) << 3);
    }
  }
  // ---- halo rows (r0-2, r0-1, r0+32, r0+33): load-or-zero, unconditional write ----
  if (tid < 64) {
    int sel = tid >> 4, q = tid & 15;
    int i = (sel < 2) ? sel : sel + 32;   // xp row index 0,1,34,35
    int r = r0 - 2 + i;
    float4 v = make_float4(0.f, 0.f, 0.f, 0.f);
    if ((unsigned)r < 64u)
      v = *reinterpret_cast<const float4*>(xb + r * 64 + (q << 2));
    float2* d2 = reinterpret_cast<float2*>(&xp[i * 68 + 2 + (q << 2)]);
    d2[0] = make_float2(v.x, v.y);
    d2[1] = make_float2(v.z, v.w);
  }
  __syncthreads();

  // ---- active-quad lists from Rm ----
  for (int g = tid; g < 512; g += BDIM) {
    int k = g >> 4, q0 = (g & 15) << 2;
    unsigned bits = (unsigned)(Rm[k] >> q0) & 0xFu;
    if (!bits) continue;
    int p = r0 + k;
    bool inter = ((unsigned)(p - 2) < 60u) && ((unsigned)(q0 - 4) <= 52u);
    if (inter) {
      aqi[atomicAdd(&nqi_sh, 1)] = (unsigned short)g;
    } else {
      aqb[atomicAdd(&nqb_sh, 1)] = (unsigned short)g;
    }
  }
  __syncthreads();

  const int nqi = nqi_sh, nqb = nqb_sh;
  float* outb = out + (size_t)b * (32 * 4096);
  const int co4 = tid & 3;

  // 4 substages: one per channel octet cg, full 32-row half each
  for (int cg = 0; cg < 4; ++cg) {
    // ---- hoist interior kernels for this lane's channel pair from LDS ----
    const int co_lo = (cg << 3) + co4;
    float KA[26], KB[26];
    {
      const float* KpA = &KiL[co_lo * KC_STRIDE];
      const float* KpB = &KiL[(co_lo + 4) * KC_STRIDE];
#pragma unroll
      for (int j = 0; j < 26; ++j) { KA[j] = KpA[j]; KB[j] = KpB[j]; }
    }
    // ---- interior quads: item = (quad, co4); thread computes co and co+4 ----
    for (int n = tid; n < nqi * 4; n += BDIM) {
      int g = aqi[n >> 2];
      int k = g >> 4, q0 = (g & 15) << 2;
      float ba = KA[25], bbv = KB[25];
      float a0 = ba, a1 = ba, a2 = ba, a3 = ba;
      float b0 = bbv, b1 = bbv, b2 = bbv, b3 = bbv;
#pragma unroll
      for (int u = 0; u < 5; ++u) {
        const float* xr = &xp[(k + u) * 68 + q0];
        float4 xa = *reinterpret_cast<const float4*>(xr);
        float4 xc = *reinterpret_cast<const float4*>(xr + 4);
        float xv[8] = {xa.x, xa.y, xa.z, xa.w, xc.x, xc.y, xc.z, xc.w};
#pragma unroll
        for (int v = 0; v < 5; ++v) {
          float ka = KA[u * 5 + v], kb = KB[u * 5 + v];
          a0 = fmaf(xv[v], ka, a0);
          a1 = fmaf(xv[v + 1], ka, a1);
          a2 = fmaf(xv[v + 2], ka, a2);
          a3 = fmaf(xv[v + 3], ka, a3);
          b0 = fmaf(xv[v], kb, b0);
          b1 = fmaf(xv[v + 1], kb, b1);
          b2 = fmaf(xv[v + 2], kb, b2);
          b3 = fmaf(xv[v + 3], kb, b3);
        }
      }
      int so = (k << 6) + q0;
      *reinterpret_cast<float4*>(&S[co4][so]) = make_float4(a0, a1, a2, a3);
      *reinterpret_cast<float4*>(&S[co4 + 4][so]) = make_float4(b0, b1, b2, b3);
    }
    // ---- border quads: item = (quad, cs of 8); per-pixel case, K from L2 ----
    for (int n = tid; n < nqb * 8; n += BDIM) {
      int g = aqb[n >> 3];
      int cs = n & 7;  // lane-static
      int co = (cg << 3) + cs;
      int k = g >> 4, q0 = (g & 15) << 2;
      int p = r0 + k;
      int cp = casef(p);
      const float* K0 = ws + ((cp * 5 + casef(q0)) * 32 + co) * KC_STRIDE;
      const float* K1 = ws + ((cp * 5 + casef(q0 + 1)) * 32 + co) * KC_STRIDE;
      const float* K2 = ws + ((cp * 5 + casef(q0 + 2)) * 32 + co) * KC_STRIDE;
      const float* K3 = ws + ((cp * 5 + casef(q0 + 3)) * 32 + co) * KC_STRIDE;
      float z0 = K0[25], z1 = K1[25], z2 = K2[25], z3 = K3[25];
#pragma unroll
      for (int u = 0; u < 5; ++u) {
        const float* xr = &xp[(k + u) * 68 + q0];
        float4 xa = *reinterpret_cast<const float4*>(xr);
        float4 xc = *reinterpret_cast<const float4*>(xr + 4);
        float xv[8] = {xa.x, xa.y, xa.z, xa.w, xc.x, xc.y, xc.z, xc.w};
#pragma unroll
        for (int v = 0; v < 5; ++v) {
          int o = u * 5 + v;
          z0 = fmaf(xv[v], K0[o], z0);
          z1 = fmaf(xv[v + 1], K1[o], z1);
          z2 = fmaf(xv[v + 2], K2[o], z2);
          z3 = fmaf(xv[v + 3], K3[o], z3);
        }
      }
      *reinterpret_cast<float4*>(&S[cs][(k << 6) + q0]) =
          make_float4(z0, z1, z2, z3);
    }
    // ---- drain-free barrier: LDS visibility only; stores stay in flight ----
    asm volatile("s_waitcnt lgkmcnt(0)" ::: "memory");
    __builtin_amdgcn_s_barrier();
    // ---- dump: wave w -> planes w and w+4 (32 rows each), NT stores ----
    {
      int co_a = (cg << 3) + wave;
      float* dstA = outb + (((size_t)co_a) << 12) + (r0 << 6);
      float* dstB = outb + (((size_t)(co_a + 4)) << 12) + (r0 << 6);
      const floatx4* SpA = reinterpret_cast<const floatx4*>(&S[wave][0]);
      const floatx4* SpB = reinterpret_cast<const floatx4*>(&S[wave + 4][0]);
#pragma unroll
      for (int i = 0; i < 8; ++i) {
        int f4 = (i << 6) + lane;
        int kk = f4 >> 4, q0 = (f4 & 15) << 2;
        unsigned bits = (unsigned)(Rm[kk] >> q0) & 0xFu;
        floatx4 va = SpA[f4];
        floatx4 vb = SpB[f4];
        if (!(bits & 1u)) { va.x = 0.f; vb.x = 0.f; }
        if (!(bits & 2u)) { va.y = 0.f; vb.y = 0.f; }
        if (!(bits & 4u)) { va.z = 0.f; vb.z = 0.f; }
        if (!(bits & 8u)) { va.w = 0.f; vb.w = 0.f; }
        __builtin_nontemporal_store(va, reinterpret_cast<floatx4*>(dstA + (f4 << 2)));
        __builtin_nontemporal_store(vb, reinterpret_cast<floatx4*>(dstB + (f4 << 2)));
      }
    }
    // ---- WAR barrier before next substage overwrites S ----
    asm volatile("s_waitcnt lgkmcnt(0)" ::: "memory");
    __builtin_amdgcn_s_barrier();
  }
}

extern "C" void kernel_launch(void* const* d_in, const int* in_sizes, int n_in,
                              void* d_out, int out_size, void* d_ws, size_t ws_size,
                              hipStream_t stream) {
  const float* x  = (const float*)d_in[0];
  const float* W1 = (const float*)d_in[1];
  const float* b1 = (const float*)d_in[2];
  const float* W2 = (const float*)d_in[3];
  const float* b2 = (const float*)d_in[4];
  float* out = (float*)d_out;
  float* ws  = (float*)d_ws;
  int B = in_sizes[0] / 4096;  // 1024 images of 64x64x1

  hipLaunchKernelGGL(prep_kernel, dim3(25), dim3(BDIM), 0, stream, W1, b1, W2, b2, ws);
  hipLaunchKernelGGL(main_kernel, dim3(2 * B), dim3(BDIM), 0, stream, x, ws, out);
}

// Round 28
// 121.492 us; speedup vs baseline: 1.2150x; 1.0010x over previous
//
#include <hip/hip_runtime.h>

#define BDIM 256
#define KC_STRIDE 28                  // per (case,co): K[0..24], bias at [25], 2 pad
#define CASE_STRIDE (32 * KC_STRIDE)  // 896 floats per border-case
#define SP 2052                       // S plane stride (32 rows x 64 + 4 pad)

typedef float floatx4 __attribute__((ext_vector_type(4)));

// case index along one axis: 0 (p==0), 1 (p==1), 2 (interior), 3 (p==62), 4 (p==63)
__device__ __forceinline__ int casef(int p) {
  return ((unsigned)(p - 2) < 60u) ? 2 : (p < 2 ? p : p - 59);
}

// spread 16 bits to stride-4 positions (bit i -> bit 4i)
__device__ __forceinline__ unsigned long long spread4(unsigned x) {
  unsigned long long v = x & 0xFFFFull;
  v = (v | (v << 24)) & 0x000000FF000000FFull;
  v = (v | (v << 12)) & 0x000F000F000F000Full;
  v = (v | (v << 6))  & 0x0303030303030303ull;
  v = (v | (v << 3))  & 0x1111111111111111ull;
  return v;
}

// ---------------- prep: collapsed 5x5 kernels, layout [case][co][28] ----------------
__global__ __launch_bounds__(BDIM) void prep_kernel(
    const float* __restrict__ W1, const float* __restrict__ b1,
    const float* __restrict__ W2, const float* __restrict__ b2,
    float* __restrict__ ws) {
  __shared__ float Mlds[9 * 9 * 32];
  __shared__ float BvL[9 * 32];
  const int tid = threadIdx.x;
  const int co = tid & 31;
  for (int tap = tid >> 5; tap < 9; tap += 8) {
    float acc[9] = {0.f, 0.f, 0.f, 0.f, 0.f, 0.f, 0.f, 0.f, 0.f};
    float accB = 0.f;
    for (int ci = 0; ci < 64; ++ci) {
      float w2 = W2[(tap * 64 + ci) * 32 + co];
      accB = fmaf(b1[ci], w2, accB);
#pragma unroll
      for (int e = 0; e < 9; ++e) acc[e] = fmaf(W1[e * 64 + ci], w2, acc[e]);
    }
#pragma unroll
    for (int e = 0; e < 9; ++e) Mlds[(tap * 9 + e) * 32 + co] = acc[e];
    BvL[tap * 32 + co] = accB;
  }
  __syncthreads();

  const int a = blockIdx.x / 5, c = blockIdx.x % 5;
  const int dmask[5] = {4, 6, 7, 3, 1};
  const int Da = dmask[a], Dc = dmask[c];
  for (int t = tid; t < CASE_STRIDE; t += BDIM) {
    int cc = t / KC_STRIDE, r = t % KC_STRIDE;
    float s = 0.f;
    if (r < 25) {
      int u = r / 5, v = r % 5;
      for (int di = 0; di < 3; ++di) {
        if (!((Da >> di) & 1)) continue;
        int ei = u - di;
        if ((unsigned)ei > 2u) continue;
        for (int dj = 0; dj < 3; ++dj) {
          if (!((Dc >> dj) & 1)) continue;
          int ej = v - dj;
          if ((unsigned)ej > 2u) continue;
          s += Mlds[((di * 3 + dj) * 9 + ei * 3 + ej) * 32 + cc];
        }
      }
    } else if (r == 25) {
      s = b2[cc];
      for (int di = 0; di < 3; ++di)
        if ((Da >> di) & 1)
          for (int dj = 0; dj < 3; ++dj)
            if ((Dc >> dj) & 1) s += BvL[(di * 3 + dj) * 32 + cc];
    }
    ws[blockIdx.x * CASE_STRIDE + t] = s;
  }
}

// ---- main: R26 + dump adjacency remap: wave w dumps ADJACENT channels
// ---- (2w, 2w+1) of the octet -> one contiguous ~32 KB store span per wave ----
__global__ __launch_bounds__(BDIM) void main_kernel(
    const float* __restrict__ x, const float* __restrict__ ws,
    float* __restrict__ out) {
  const int bb = blockIdx.x;
  const int b = bb >> 1;
  const int r0 = (bb & 1) << 5;  // 0 or 32
  const int tid = threadIdx.x;
  const int lane = tid & 63;
  const int wave = tid >> 6;

  __shared__ __align__(16) float xp[36 * 68];       // rows r0-2..r0+33, cols -2..65
  __shared__ __align__(16) float S[8][SP];          // 8 planes of 32x64 (+pad)
  __shared__ __align__(16) float KiL[CASE_STRIDE];  // interior case (2,2), 32 ch
  __shared__ unsigned long long Rm[32];
  __shared__ unsigned short aqi[448], aqb[128];
  __shared__ int nqi_sh, nqb_sh;

  if (tid == 0) { nqi_sh = 0; nqb_sh = 0; }
  for (int i = tid; i < CASE_STRIDE; i += BDIM) KiL[i] = ws[12 * CASE_STRIDE + i];

  const float* xb = x + (size_t)b * 4096;

  // ---- col-halo zero (cols 0,1,66,67 of all 36 xp rows; 144 floats) ----
  if (tid < 144) {
    int i = tid >> 2, c = tid & 3;
    xp[i * 68 + ((c & 1) + ((c >> 1) * 66))] = 0.f;
  }
  // ---- fused own-row load + ballot (rows r0..r0+31, always in-bounds) ----
#pragma unroll
  for (int j = 0; j < 2; ++j) {
    int it = tid + (j << 8);
    int k = it >> 4;           // 0..31 own-row index
    int q = it & 15;           // quad
    float4 v = *reinterpret_cast<const float4*>(xb + (r0 + k) * 64 + (q << 2));
    float2* d2 = reinterpret_cast<float2*>(&xp[(k + 2) * 68 + 2 + (q << 2)]);
    d2[0] = make_float2(v.x, v.y);
    d2[1] = make_float2(v.z, v.w);
    unsigned long long b0 = __ballot(v.x != 0.f);
    unsigned long long b1 = __ballot(v.y != 0.f);
    unsigned long long b2 = __ballot(v.z != 0.f);
    unsigned long long b3 = __ballot(v.w != 0.f);
    if ((lane & 15) == 0) {
      int rslice = lane >> 4;
      unsigned s0 = (unsigned)((b0 >> (rslice << 4)) & 0xFFFFu);
      unsigned s1 = (unsigned)((b1 >> (rslice << 4)) & 0xFFFFu);
      unsigned s2 = (unsigned)((b2 >> (rslice << 4)) & 0xFFFFu);
      unsigned s3 = (unsigned)((b3 >> (rslice << 4)) & 0xFFFFu);
      Rm[k] = spread4(s0) | (spread4(s1) << 1) | (spread4(s2) << 2) |
              (spread4(s3) << 3);
    }
  }
  // ---- halo rows (r0-2, r0-1, r0+32, r0+33): load-or-zero, unconditional ----
  if (tid < 64) {
    int sel = tid >> 4, q = tid & 15;
    int i = (sel < 2) ? sel : sel + 32;   // xp row index 0,1,34,35
    int r = r0 - 2 + i;
    float4 v = make_float4(0.f, 0.f, 0.f, 0.f);
    if ((unsigned)r < 64u)
      v = *reinterpret_cast<const float4*>(xb + r * 64 + (q << 2));
    float2* d2 = reinterpret_cast<float2*>(&xp[i * 68 + 2 + (q << 2)]);
    d2[0] = make_float2(v.x, v.y);
    d2[1] = make_float2(v.z, v.w);
  }
  __syncthreads();

  // ---- active-quad lists from Rm ----
  for (int g = tid; g < 512; g += BDIM) {
    int k = g >> 4, q0 = (g & 15) << 2;
    unsigned bits = (unsigned)(Rm[k] >> q0) & 0xFu;
    if (!bits) continue;
    int p = r0 + k;
    bool inter = ((unsigned)(p - 2) < 60u) && ((unsigned)(q0 - 4) <= 52u);
    if (inter) {
      aqi[atomicAdd(&nqi_sh, 1)] = (unsigned short)g;
    } else {
      aqb[atomicAdd(&nqb_sh, 1)] = (unsigned short)g;
    }
  }
  __syncthreads();

  const int nqi = nqi_sh, nqb = nqb_sh;
  float* outb = out + (size_t)b * (32 * 4096);
  const int co4 = tid & 3;

  // 4 substages: one per channel octet cg, full 32-row half each
  for (int cg = 0; cg < 4; ++cg) {
    // ---- hoist interior kernels for this lane's channel pair from LDS ----
    const int co_lo = (cg << 3) + co4;
    float KA[26], KB[26];
    {
      const float* KpA = &KiL[co_lo * KC_STRIDE];
      const float* KpB = &KiL[(co_lo + 4) * KC_STRIDE];
#pragma unroll
      for (int j = 0; j < 26; ++j) { KA[j] = KpA[j]; KB[j] = KpB[j]; }
    }
    // ---- interior quads: item = (quad, co4); thread computes co and co+4 ----
    for (int n = tid; n < nqi * 4; n += BDIM) {
      int g = aqi[n >> 2];
      int k = g >> 4, q0 = (g & 15) << 2;
      float ba = KA[25], bbv = KB[25];
      float a0 = ba, a1 = ba, a2 = ba, a3 = ba;
      float b0 = bbv, b1 = bbv, b2 = bbv, b3 = bbv;
#pragma unroll
      for (int u = 0; u < 5; ++u) {
        const float* xr = &xp[(k + u) * 68 + q0];
        float4 xa = *reinterpret_cast<const float4*>(xr);
        float4 xc = *reinterpret_cast<const float4*>(xr + 4);
        float xv[8] = {xa.x, xa.y, xa.z, xa.w, xc.x, xc.y, xc.z, xc.w};
#pragma unroll
        for (int v = 0; v < 5; ++v) {
          float ka = KA[u * 5 + v], kb = KB[u * 5 + v];
          a0 = fmaf(xv[v], ka, a0);
          a1 = fmaf(xv[v + 1], ka, a1);
          a2 = fmaf(xv[v + 2], ka, a2);
          a3 = fmaf(xv[v + 3], ka, a3);
          b0 = fmaf(xv[v], kb, b0);
          b1 = fmaf(xv[v + 1], kb, b1);
          b2 = fmaf(xv[v + 2], kb, b2);
          b3 = fmaf(xv[v + 3], kb, b3);
        }
      }
      int so = (k << 6) + q0;
      *reinterpret_cast<float4*>(&S[co4][so]) = make_float4(a0, a1, a2, a3);
      *reinterpret_cast<float4*>(&S[co4 + 4][so]) = make_float4(b0, b1, b2, b3);
    }
    // ---- border quads: item = (quad, cs of 8); per-pixel case, K from L2 ----
    for (int n = tid; n < nqb * 8; n += BDIM) {
      int g = aqb[n >> 3];
      int cs = n & 7;  // lane-static
      int co = (cg << 3) + cs;
      int k = g >> 4, q0 = (g & 15) << 2;
      int p = r0 + k;
      int cp = casef(p);
      const float* K0 = ws + ((cp * 5 + casef(q0)) * 32 + co) * KC_STRIDE;
      const float* K1 = ws + ((cp * 5 + casef(q0 + 1)) * 32 + co) * KC_STRIDE;
      const float* K2 = ws + ((cp * 5 + casef(q0 + 2)) * 32 + co) * KC_STRIDE;
      const float* K3 = ws + ((cp * 5 + casef(q0 + 3)) * 32 + co) * KC_STRIDE;
      float z0 = K0[25], z1 = K1[25], z2 = K2[25], z3 = K3[25];
#pragma unroll
      for (int u = 0; u < 5; ++u) {
        const float* xr = &xp[(k + u) * 68 + q0];
        float4 xa = *reinterpret_cast<const float4*>(xr);
        float4 xc = *reinterpret_cast<const float4*>(xr + 4);
        float xv[8] = {xa.x, xa.y, xa.z, xa.w, xc.x, xc.y, xc.z, xc.w};
#pragma unroll
        for (int v = 0; v < 5; ++v) {
          int o = u * 5 + v;
          z0 = fmaf(xv[v], K0[o], z0);
          z1 = fmaf(xv[v + 1], K1[o], z1);
          z2 = fmaf(xv[v + 2], K2[o], z2);
          z3 = fmaf(xv[v + 3], K3[o], z3);
        }
      }
      *reinterpret_cast<float4*>(&S[cs][(k << 6) + q0]) =
          make_float4(z0, z1, z2, z3);
    }
    // ---- drain-free barrier: LDS visibility only; stores stay in flight ----
    asm volatile("s_waitcnt lgkmcnt(0)" ::: "memory");
    __builtin_amdgcn_s_barrier();
    // ---- dump: wave w -> ADJACENT channels (2w, 2w+1): S planes map
    // ---- co&7: 2w -> plane index (2w)&3 if 2w<4 else... channel c's plane is
    // ---- [c&3 + 4*(c>>2 & 1)] = c&7; for c=2w: plane 2w; c=2w+1: plane 2w+1.
    {
      int cA = (cg << 3) + (wave << 1);      // even channel of pair
      int cB = cA + 1;
      float* dstA = outb + (((size_t)cA) << 12) + (r0 << 6);
      float* dstB = outb + (((size_t)cB) << 12) + (r0 << 6);
      // channel c lives in S plane: (c&3) + 4*((c>>2)&1) == c&7
      const floatx4* SpA = reinterpret_cast<const floatx4*>(&S[(wave << 1) & 7][0]);
      const floatx4* SpB = reinterpret_cast<const floatx4*>(&S[((wave << 1) + 1) & 7][0]);
#pragma unroll
      for (int i = 0; i < 8; ++i) {
        int f4 = (i << 6) + lane;
        int kk = f4 >> 4, q0 = (f4 & 15) << 2;
        unsigned bits = (unsigned)(Rm[kk] >> q0) & 0xFu;
        floatx4 va = SpA[f4];
        floatx4 vb = SpB[f4];
        if (!(bits & 1u)) { va.x = 0.f; vb.x = 0.f; }
        if (!(bits & 2u)) { va.y = 0.f; vb.y = 0.f; }
        if (!(bits & 4u)) { va.z = 0.f; vb.z = 0.f; }
        if (!(bits & 8u)) { va.w = 0.f; vb.w = 0.f; }
        __builtin_nontemporal_store(va, reinterpret_cast<floatx4*>(dstA + (f4 << 2)));
        __builtin_nontemporal_store(vb, reinterpret_cast<floatx4*>(dstB + (f4 << 2)));
      }
    }
    // ---- WAR barrier before next substage overwrites S ----
    asm volatile("s_waitcnt lgkmcnt(0)" ::: "memory");
    __builtin_amdgcn_s_barrier();
  }
}

extern "C" void kernel_launch(void* const* d_in, const int* in_sizes, int n_in,
                              void* d_out, int out_size, void* d_ws, size_t ws_size,
                              hipStream_t stream) {
  const float* x  = (const float*)d_in[0];
  const float* W1 = (const float*)d_in[1];
  const float* b1 = (const float*)d_in[2];
  const float* W2 = (const float*)d_in[3];
  const float* b2 = (const float*)d_in[4];
  float* out = (float*)d_out;
  float* ws  = (float*)d_ws;
  int B = in_sizes[0] / 4096;  // 1024 images of 64x64x1

  hipLaunchKernelGGL(prep_kernel, dim3(25), dim3(BDIM), 0, stream, W1, b1, W2, b2, ws);
  hipLaunchKernelGGL(main_kernel, dim3(2 * B), dim3(BDIM), 0, stream, x, ws, out);
}